// Round 19
// baseline (120.270 us; speedup 1.0000x reference)
//
#include <hip/hip_runtime.h>
#include <hip/hip_bf16.h>

#define NGROUP 256   // B * (SEQ/TG)
#define NSLOT  128   // experts * sets
#define TG     32    // tokens per group
#define DM     1024  // model dim
#define FF     32    // expert size

#define LSCALE     4096.0f
#define INV_LSCALE (1.0f / 4096.0f)

typedef unsigned int  uint;
typedef unsigned short ushort;
typedef unsigned char uchar;
typedef __attribute__((ext_vector_type(4))) float f32x4;
typedef __attribute__((ext_vector_type(8))) short bf16x8;
typedef __attribute__((ext_vector_type(8))) _Float16 f16x8;

__device__ __forceinline__ ushort f2bf(float f) {
    uint u = __float_as_uint(f);
    u += 0x7FFFu + ((u >> 16) & 1u);   // RNE
    return (ushort)(u >> 16);
}
__device__ __forceinline__ uint pk2(float a, float b) {
    return (uint)f2bf(a) | ((uint)f2bf(b) << 16);
}

// async global->LDS, 16B per lane; dst wave-uniform base (+lane*16 implicit)
__device__ __forceinline__ void gload_lds16(const void* g, void* l) {
    __builtin_amdgcn_global_load_lds(
        (const __attribute__((address_space(1))) uint*)g,
        (__attribute__((address_space(3))) uint*)l, 16, 0, 0);
}

// ---------------------------------------------------------------------------
// K1 mega-kernel (v19): one launch, three block families, 64 KB dyn LDS.
//  blocks 0..255   : logits (ALL 128 slots per group -> x read/split ONCE)
//                    + tie-broken argmax + fused x->bf16 cast (+idx8)
//  blocks 256..511 : f1 -> f1F bf16 (MFMA-B fragment order)
//  blocks 512..1023: f2 -> f2T[es][d][f] bf16
// Per-wave K-chunks, split math, MFMA order, plane-reduce association and
// argmax comparisons element-identical to v18 -> idx/xb bit-identical.
// ---------------------------------------------------------------------------
__global__ __launch_bounds__(256) void k_fused1(
    const float* __restrict__ x, const float* __restrict__ ctrl,
    const float* __restrict__ f1, const float* __restrict__ f2,
    int* __restrict__ idx, uchar* __restrict__ idx8, ushort* __restrict__ xb,
    ushort* __restrict__ f1F, ushort* __restrict__ f2T)
{
    extern __shared__ char fsm[];   // 64 KB
    const int t = threadIdx.x;

    if (blockIdx.x < 256) {
        // -------- logits + argmax, full 128 slots per block ---------------
        float* Lp = (float*)fsm;    // [4 planes][32 t][128 n] = 64 KB
        const int g = blockIdx.x;
        const int w = t >> 6;
        const int lane = t & 63;
        const int lrow = lane & 15;
        const int lk8 = (lane >> 4) * 8;

        const size_t xoff0 = ((size_t)g * TG + lrow) * DM + w * 256 + lk8;
        const float* xr0 = x + xoff0;
        const float* xr1 = xr0 + 16 * DM;

        f32x4 ahh[2][8], ax[2][8];
#pragma unroll
        for (int mt = 0; mt < 2; ++mt)
#pragma unroll
            for (int nt = 0; nt < 8; ++nt) {
                ahh[mt][nt] = (f32x4){0.f, 0.f, 0.f, 0.f};
                ax[mt][nt]  = (f32x4){0.f, 0.f, 0.f, 0.f};
            }

        for (int ks = 0; ks < 8; ++ks) {
            f16x8 Ah[2], Al[2];
#pragma unroll
            for (int mt = 0; mt < 2; ++mt) {
                const float* p = (mt ? xr1 : xr0) + ks * 32;
                float xe[8];
                *(float4*)&xe[0] = *(const float4*)p;
                *(float4*)&xe[4] = *(const float4*)(p + 4);
                union { f16x8 v; _Float16 e[8]; } H, L;
#pragma unroll
                for (int j = 0; j < 8; ++j) {
                    const _Float16 h = (_Float16)xe[j];
                    H.e[j] = h;
                    L.e[j] = (_Float16)((xe[j] - (float)h) * LSCALE);
                }
                Ah[mt] = H.v; Al[mt] = L.v;
                // x->bf16 cast, once per element (identical RNE values)
                uint4 o;
                o.x = pk2(xe[0], xe[1]); o.y = pk2(xe[2], xe[3]);
                o.z = pk2(xe[4], xe[5]); o.w = pk2(xe[6], xe[7]);
                *(uint4*)(xb + xoff0 + (size_t)mt * 16 * DM + ks * 32) = o;
            }
            const int kslice = w * 8 + ks;
#pragma unroll
            for (int nt = 0; nt < 8; ++nt) {
                const float* cp = ctrl
                    + (size_t)(kslice * 32 + ((lane >> 4) << 3)) * NSLOT
                    + nt * 16 + (lane & 15);
                union { f16x8 v; _Float16 e[8]; } BH, BL;
#pragma unroll
                for (int j = 0; j < 8; ++j) {
                    const float c = cp[(size_t)j * NSLOT];
                    const _Float16 h = (_Float16)c;
                    BH.e[j] = h;
                    BL.e[j] = (_Float16)((c - (float)h) * LSCALE);
                }
#pragma unroll
                for (int mt = 0; mt < 2; ++mt) {
                    ahh[mt][nt] = __builtin_amdgcn_mfma_f32_16x16x32_f16(Ah[mt], BH.v, ahh[mt][nt], 0, 0, 0);
                    ax[mt][nt]  = __builtin_amdgcn_mfma_f32_16x16x32_f16(Al[mt], BH.v, ax[mt][nt], 0, 0, 0);
                    ax[mt][nt]  = __builtin_amdgcn_mfma_f32_16x16x32_f16(Ah[mt], BL.v, ax[mt][nt], 0, 0, 0);
                }
            }
        }

#pragma unroll
        for (int mt = 0; mt < 2; ++mt)
#pragma unroll
            for (int nt = 0; nt < 8; ++nt)
#pragma unroll
                for (int r = 0; r < 4; ++r) {
                    const int trow = mt * 16 + (lane >> 4) * 4 + r;
                    const int nl = nt * 16 + lrow;
                    Lp[(w * TG + trow) * NSLOT + nl] =
                        ahh[mt][nt][r] + ax[mt][nt][r] * INV_LSCALE;
                }
        __syncthreads();

        // reduce 4 wave planes into plane 0 (same association as v18)
        for (int i = t * 4; i < TG * NSLOT; i += 256 * 4) {
            f32x4 s0 = *(const f32x4*)&Lp[i];
            f32x4 s1 = *(const f32x4*)&Lp[4096 + i];
            f32x4 s2 = *(const f32x4*)&Lp[8192 + i];
            f32x4 s3 = *(const f32x4*)&Lp[12288 + i];
            *(f32x4*)&Lp[i] = (s0 + s1) + (s2 + s3);
        }
        __syncthreads();

        if (t < NSLOT) {
            const int n = t;
            float best = -1e30f;
            int bi = 0;
#pragma unroll
            for (int tt = 0; tt < TG; ++tt) {
                const float v = Lp[tt * NSLOT + n] + (float)tt * (1e-6f / 31.0f);
                if (v >= best) { best = v; bi = tt; }   // later token wins ties
            }
            idx[g * NSLOT + n] = bi;
            idx8[g * NSLOT + n] = (uchar)bi;
        }
    } else if (blockIdx.x < 512) {
        float* Ltr = (float*)fsm;   // [64][33]
        const int i1 = blockIdx.x - 256;
        const int es = i1 >> 1;
        const int dh = i1 & 1;
        for (int d0 = dh * 512; d0 < dh * 512 + 512; d0 += 64) {
            const int dd = t >> 2, f0 = (t & 3) * 8;
            const float* src = f1 + (size_t)(d0 + dd) * 4096 + es * FF + f0;
            float4 a = *(const float4*)src;
            float4 b = *(const float4*)(src + 4);
            __syncthreads();
            float* Lq = &Ltr[dd * 33 + f0];
            Lq[0] = a.x; Lq[1] = a.y; Lq[2] = a.z; Lq[3] = a.w;
            Lq[4] = b.x; Lq[5] = b.y; Lq[6] = b.z; Lq[7] = b.w;
            __syncthreads();
            const int f = t & 31, koct = t >> 5;
            const int nt = f >> 4;
            const int kg = d0 + koct * 8;
            const int kslice = kg >> 5;
            const int lane2 = (f & 15) | (((kg >> 3) & 3) << 4);
            uint4 o;
            o.x = pk2(Ltr[(koct * 8 + 0) * 33 + f], Ltr[(koct * 8 + 1) * 33 + f]);
            o.y = pk2(Ltr[(koct * 8 + 2) * 33 + f], Ltr[(koct * 8 + 3) * 33 + f]);
            o.z = pk2(Ltr[(koct * 8 + 4) * 33 + f], Ltr[(koct * 8 + 5) * 33 + f]);
            o.w = pk2(Ltr[(koct * 8 + 6) * 33 + f], Ltr[(koct * 8 + 7) * 33 + f]);
            *(uint4*)(f1F + ((((size_t)es * 2 + nt) * 32 + kslice) * 64 + lane2) * 8) = o;
        }
    } else {
        float* Ltr = (float*)fsm;   // [64][33]
        const int i2 = blockIdx.x - 512;
        const int es = i2 >> 2;
        const int dq = i2 & 3;
        for (int d0 = dq * 256; d0 < dq * 256 + 256; d0 += 64) {
            const int f = t >> 3, ds = (t & 7) * 8;
            const float* src = f2 + (size_t)es * (FF * DM) + f * DM + d0 + ds;
            float4 a = *(const float4*)src;
            float4 b = *(const float4*)(src + 4);
            __syncthreads();
            Ltr[(ds + 0) * 33 + f] = a.x; Ltr[(ds + 1) * 33 + f] = a.y;
            Ltr[(ds + 2) * 33 + f] = a.z; Ltr[(ds + 3) * 33 + f] = a.w;
            Ltr[(ds + 4) * 33 + f] = b.x; Ltr[(ds + 5) * 33 + f] = b.y;
            Ltr[(ds + 6) * 33 + f] = b.z; Ltr[(ds + 7) * 33 + f] = b.w;
            __syncthreads();
            const int dd = t >> 2, f0 = (t & 3) * 8;
            uint4 o;
            o.x = pk2(Ltr[dd * 33 + f0 + 0], Ltr[dd * 33 + f0 + 1]);
            o.y = pk2(Ltr[dd * 33 + f0 + 2], Ltr[dd * 33 + f0 + 3]);
            o.z = pk2(Ltr[dd * 33 + f0 + 4], Ltr[dd * 33 + f0 + 5]);
            o.w = pk2(Ltr[dd * 33 + f0 + 6], Ltr[dd * 33 + f0 + 7]);
            *(uint4*)(f2T + (size_t)es * (FF * DM) + (d0 + dd) * FF + f0) = o;
        }
    }
}

// ---------------------------------------------------------------------------
// K2: H = relu(x_gathered @ f1 + bias) via MFMA. LDS-free. UNCHANGED (v18).
// ---------------------------------------------------------------------------
__global__ __launch_bounds__(256) void k_h_mfma(
    const ushort* __restrict__ xb, const ushort* __restrict__ f1F,
    const float* __restrict__ bias, const int* __restrict__ idx,
    ushort* __restrict__ Hb)
{
    const int es = blockIdx.x >> 2;
    const int gq = blockIdx.x & 3;
    const int w = threadIdx.x >> 6;
    const int lane = threadIdx.x & 63;
    const int lrow = lane & 15;
    const int lk8 = (lane >> 4) * 8;

    const int ga = gq * 64 + w * 16 + lrow;
    const int tok = idx[ga * NSLOT + es];
    const ushort* abase = xb + ((size_t)ga * TG + tok) * DM + lk8;
    const ushort* bbase = f1F + (size_t)es * 2 * 32 * 512 + (size_t)lane * 8;

    f32x4 acc[2] = {(f32x4){0.f, 0.f, 0.f, 0.f}, (f32x4){0.f, 0.f, 0.f, 0.f}};

#pragma unroll 4
    for (int kslice = 0; kslice < 32; ++kslice) {
        const bf16x8 A = *(const bf16x8*)(abase + kslice * 32);
#pragma unroll
        for (int nt = 0; nt < 2; ++nt) {
            const bf16x8 B = *(const bf16x8*)(bbase + ((size_t)nt * 32 + kslice) * 512);
            acc[nt] = __builtin_amdgcn_mfma_f32_16x16x32_bf16(A, B, acc[nt], 0, 0, 0);
        }
    }

#pragma unroll
    for (int nt = 0; nt < 2; ++nt) {
        const int f = nt * 16 + lrow;
        const float bv = bias[es * FF + f];
#pragma unroll
        for (int r = 0; r < 4; ++r) {
            const int g = gq * 64 + w * 16 + (lane >> 4) * 4 + r;
            const float hv = fmaxf(acc[nt][r] + bv, 0.0f);
            Hb[(size_t)g * (NSLOT * FF) + es * FF + f] = f2bf(hv);
        }
    }
}

// ---------------------------------------------------------------------------
// K3 (v18, UNCHANGED): 16 distinct groups x 64 d per block, grid 256 =
// 1 block/CU, single round; A+B LDS ring (distance 3, vmcnt(6)); OL 128 KB
// with (dq<<4)|(dq^g) slot swizzle (<=2-way banks); idx8 in registers.
// ---------------------------------------------------------------------------
__global__ __launch_bounds__(256) void k_out_mfma(
    const ushort* __restrict__ Hb, const ushort* __restrict__ f2T,
    const uchar* __restrict__ idx8, float* __restrict__ out)
{
    extern __shared__ char smK3[];
    float* OL   = (float*)smK3;                // [32 t][256 16B-slots] = 128 KB
    char*  Ring = smK3 + 131072;               // [4 w][4 slots][2048 B] = 32 KB

    const int D0 = (blockIdx.x & 15) * 64;     // db-minor (proven order)
    const int G0 = (blockIdx.x >> 4) * 16;
    const int tid = threadIdx.x;
    const int w = tid >> 6;
    const int lane = tid & 63;
    const int gl = lane & 15;                  // group (B col) AND A d-row
    const int sq = lane >> 4;                  // k-slice 0..3
    const int dq = w * 4 + sq;                 // d-quad 0..15

    for (int i = tid * 4; i < 32768; i += 1024)
        *(f32x4*)&OL[i] = (f32x4){0.f, 0.f, 0.f, 0.f};
    uint ui[32];
    {
        const uint4* p = (const uint4*)(idx8 + (size_t)(G0 + gl) * NSLOT);
#pragma unroll
        for (int k = 0; k < 8; ++k) {
            const uint4 v = p[k];
            ui[k * 4 + 0] = v.x; ui[k * 4 + 1] = v.y;
            ui[k * 4 + 2] = v.z; ui[k * 4 + 3] = v.w;
        }
    }
    __syncthreads();

    const ushort* ap  = f2T + (size_t)(D0 + w * 16 + gl) * FF + sq * 8;
    const ushort* bps = Hb + (size_t)(G0 + gl) * (NSLOT * FF) + sq * 8;
    char* ring = Ring + w * 8192;

#pragma unroll
    for (int s = 0; s < 3; ++s) {
        gload_lds16(ap  + (size_t)s * (FF * DM), ring + s * 2048);
        gload_lds16(bps + (size_t)s * FF,        ring + s * 2048 + 1024);
    }

    const int sOL = (dq << 4) | (dq ^ gl);

#pragma unroll 4
    for (int e = 0; e < 128; ++e) {
        {
            const int en = (e + 3) & 127;
            char* slot = ring + ((e + 3) & 3) * 2048;
            gload_lds16(ap  + (size_t)en * (FF * DM), slot);
            gload_lds16(bps + (size_t)en * FF,        slot + 1024);
        }
        asm volatile("s_waitcnt vmcnt(6)" ::: "memory");

        const char* slot = ring + (e & 3) * 2048;
        const bf16x8 afr = *(const bf16x8*)(slot + lane * 16);
        const bf16x8 bfr = *(const bf16x8*)(slot + 1024 + lane * 16);
        const f32x4 d = __builtin_amdgcn_mfma_f32_16x16x32_bf16(
            afr, bfr, (f32x4){0.f, 0.f, 0.f, 0.f}, 0, 0, 0);
        const uint tv = (ui[e >> 2] >> ((e & 3) * 8)) & 0xFFu;
        float* olp = &OL[tv * 1024 + sOL * 4];
        *(f32x4*)olp = *(const f32x4*)olp + d;
    }
    asm volatile("s_waitcnt vmcnt(0)" ::: "memory");
    __syncthreads();

    {
        const int g = tid >> 4, dqe = tid & 15;
        const int se = (dqe << 4) | (dqe ^ g);
#pragma unroll 4
        for (int t = 0; t < TG; ++t) {
            const f32x4 v = *(const f32x4*)&OL[t * 1024 + se * 4];
            *(f32x4*)&out[((size_t)(G0 + g) * TG + t) * DM + D0 + dqe * 4] = v;
        }
    }
}

// ---------------------------------------------------------------------------
extern "C" void kernel_launch(void* const* d_in, const int* in_sizes, int n_in,
                              void* d_out, int out_size, void* d_ws, size_t ws_size,
                              hipStream_t stream) {
    (void)in_sizes; (void)n_in; (void)out_size; (void)ws_size;
    const float* x    = (const float*)d_in[0];
    const float* ctrl = (const float*)d_in[1];
    const float* f1   = (const float*)d_in[2];
    const float* bias = (const float*)d_in[3];
    const float* f2   = (const float*)d_in[4];
    float* out = (float*)d_out;

    char* ws = (char*)d_ws;
    int*    idx  = (int*)ws;                        // 128 KB
    ushort* Hb   = (ushort*)(ws + 131072);          // 2 MB
    ushort* f1F  = (ushort*)(ws + 2228224);         // 8 MB
    ushort* f2T  = (ushort*)(ws + 10616832);        // 8 MB
    ushort* xb   = (ushort*)(ws + 19005440);        // 16 MB
    uchar*  idx8 = (uchar*)(ws + 35782656);         // 32 KB (end ~34.2 MB)

    const size_t lds1 = 65536;
    hipFuncSetAttribute((const void*)k_fused1,
                        hipFuncAttributeMaxDynamicSharedMemorySize, (int)lds1);
    k_fused1<<<1024, 256, lds1, stream>>>(x, ctrl, f1, f2, idx, idx8, xb, f1F, f2T);

    k_h_mfma<<<NSLOT * 4, 256, 0, stream>>>(xb, f1F, bias, idx, Hb);

    const size_t lds3 = 163840;                     // 160 KiB exactly
    hipFuncSetAttribute((const void*)k_out_mfma,
                        hipFuncAttributeMaxDynamicSharedMemorySize, (int)lds3);
    k_out_mfma<<<256, 256, lds3, stream>>>(Hb, f2T, idx8, out);
}

// Round 20
// 75.304 us; speedup vs baseline: 1.5971x; 1.5971x over previous
//
#include <hip/hip_runtime.h>
#include <hip/hip_bf16.h>

#define NGROUP 256   // B * (SEQ/TG)
#define NSLOT  128   // experts * sets
#define TG     32    // tokens per group
#define DM     1024  // model dim
#define FF     32    // expert size

#define LSCALE     4096.0f
#define INV_LSCALE (1.0f / 4096.0f)

typedef unsigned int  uint;
typedef unsigned short ushort;
typedef unsigned char uchar;
typedef __attribute__((ext_vector_type(4))) float f32x4;
typedef __attribute__((ext_vector_type(8))) short bf16x8;
typedef __attribute__((ext_vector_type(8))) _Float16 f16x8;

__device__ __forceinline__ ushort f2bf(float f) {
    uint u = __float_as_uint(f);
    u += 0x7FFFu + ((u >> 16) & 1u);   // RNE
    return (ushort)(u >> 16);
}
__device__ __forceinline__ uint pk2(float a, float b) {
    return (uint)f2bf(a) | ((uint)f2bf(b) << 16);
}

// async global->LDS, 16B per lane; dst wave-uniform base (+lane*16 implicit)
__device__ __forceinline__ void gload_lds16(const void* g, void* l) {
    __builtin_amdgcn_global_load_lds(
        (const __attribute__((address_space(1))) uint*)g,
        (__attribute__((address_space(3))) uint*)l, 16, 0, 0);
}

// ---------------------------------------------------------------------------
// K1 mega-kernel (v18-proven, UNCHANGED): one launch, three block families.
//  blocks 0..511    : logits + tie-broken argmax + fused x->bf16 cast (+idx8)
//  blocks 512..767  : f1 -> f1F bf16 (MFMA-B fragment order)
//  blocks 768..1279 : f2 -> f2T[es][d][f] bf16
// ---------------------------------------------------------------------------
__global__ __launch_bounds__(256) void k_fused1(
    const float* __restrict__ x, const float* __restrict__ ctrl,
    const float* __restrict__ f1, const float* __restrict__ f2,
    int* __restrict__ idx, uchar* __restrict__ idx8, ushort* __restrict__ xb,
    ushort* __restrict__ f1F, ushort* __restrict__ f2T)
{
    __shared__ float smem[4 * 32 * 64];   // 32 KB
    const int t = threadIdx.x;

    if (blockIdx.x < 512) {
        float* Lp = smem;
        const int g  = blockIdx.x >> 1;
        const int nh = blockIdx.x & 1;
        const int w = t >> 6;
        const int lane = t & 63;
        const int lrow = lane & 15;
        const int lk8 = (lane >> 4) * 8;

        const size_t xoff0 = ((size_t)g * TG + lrow) * DM + w * 256 + lk8;
        const float* xr0 = x + xoff0;
        const float* xr1 = xr0 + 16 * DM;

        f32x4 ahh[2][4], ax[2][4];
#pragma unroll
        for (int mt = 0; mt < 2; ++mt)
#pragma unroll
            for (int nt = 0; nt < 4; ++nt) {
                ahh[mt][nt] = (f32x4){0.f, 0.f, 0.f, 0.f};
                ax[mt][nt]  = (f32x4){0.f, 0.f, 0.f, 0.f};
            }

        for (int ks = 0; ks < 8; ++ks) {
            f16x8 Ah[2], Al[2];
#pragma unroll
            for (int mt = 0; mt < 2; ++mt) {
                const float* p = (mt ? xr1 : xr0) + ks * 32;
                float xe[8];
                *(float4*)&xe[0] = *(const float4*)p;
                *(float4*)&xe[4] = *(const float4*)(p + 4);
                union { f16x8 v; _Float16 e[8]; } H, L;
#pragma unroll
                for (int j = 0; j < 8; ++j) {
                    const _Float16 h = (_Float16)xe[j];
                    H.e[j] = h;
                    L.e[j] = (_Float16)((xe[j] - (float)h) * LSCALE);
                }
                Ah[mt] = H.v; Al[mt] = L.v;
                if (nh == 0) {
                    uint4 o;
                    o.x = pk2(xe[0], xe[1]); o.y = pk2(xe[2], xe[3]);
                    o.z = pk2(xe[4], xe[5]); o.w = pk2(xe[6], xe[7]);
                    *(uint4*)(xb + xoff0 + (size_t)mt * 16 * DM + ks * 32) = o;
                }
            }
            const int kslice = w * 8 + ks;
#pragma unroll
            for (int nt = 0; nt < 4; ++nt) {
                const float* cp = ctrl
                    + (size_t)(kslice * 32 + ((lane >> 4) << 3)) * NSLOT
                    + nh * 64 + nt * 16 + (lane & 15);
                union { f16x8 v; _Float16 e[8]; } BH, BL;
#pragma unroll
                for (int j = 0; j < 8; ++j) {
                    const float c = cp[(size_t)j * NSLOT];
                    const _Float16 h = (_Float16)c;
                    BH.e[j] = h;
                    BL.e[j] = (_Float16)((c - (float)h) * LSCALE);
                }
#pragma unroll
                for (int mt = 0; mt < 2; ++mt) {
                    ahh[mt][nt] = __builtin_amdgcn_mfma_f32_16x16x32_f16(Ah[mt], BH.v, ahh[mt][nt], 0, 0, 0);
                    ax[mt][nt]  = __builtin_amdgcn_mfma_f32_16x16x32_f16(Al[mt], BH.v, ax[mt][nt], 0, 0, 0);
                    ax[mt][nt]  = __builtin_amdgcn_mfma_f32_16x16x32_f16(Ah[mt], BL.v, ax[mt][nt], 0, 0, 0);
                }
            }
        }

#pragma unroll
        for (int mt = 0; mt < 2; ++mt)
#pragma unroll
            for (int nt = 0; nt < 4; ++nt)
#pragma unroll
                for (int r = 0; r < 4; ++r) {
                    const int trow = mt * 16 + (lane >> 4) * 4 + r;
                    const int nl = nt * 16 + lrow;
                    Lp[(w * TG + trow) * 64 + nl] =
                        ahh[mt][nt][r] + ax[mt][nt][r] * INV_LSCALE;
                }
        __syncthreads();

        for (int i = t * 4; i < TG * 64; i += 256 * 4) {
            f32x4 s0 = *(const f32x4*)&Lp[i];
            f32x4 s1 = *(const f32x4*)&Lp[2048 + i];
            f32x4 s2 = *(const f32x4*)&Lp[4096 + i];
            f32x4 s3 = *(const f32x4*)&Lp[6144 + i];
            *(f32x4*)&Lp[i] = (s0 + s1) + (s2 + s3);
        }
        __syncthreads();

        if (t < 64) {
            const int n = t;
            float best = -1e30f;
            int bi = 0;
#pragma unroll
            for (int tt = 0; tt < TG; ++tt) {
                const float v = Lp[tt * 64 + n] + (float)tt * (1e-6f / 31.0f);
                if (v >= best) { best = v; bi = tt; }   // later token wins ties
            }
            idx[g * NSLOT + nh * 64 + n] = bi;
            idx8[g * NSLOT + nh * 64 + n] = (uchar)bi;
        }
    } else if (blockIdx.x < 768) {
        float* Ltr = smem;   // [64][33]
        const int i1 = blockIdx.x - 512;
        const int es = i1 >> 1;
        const int dh = i1 & 1;
        for (int d0 = dh * 512; d0 < dh * 512 + 512; d0 += 64) {
            const int dd = t >> 2, f0 = (t & 3) * 8;
            const float* src = f1 + (size_t)(d0 + dd) * 4096 + es * FF + f0;
            float4 a = *(const float4*)src;
            float4 b = *(const float4*)(src + 4);
            __syncthreads();
            float* Lq = &Ltr[dd * 33 + f0];
            Lq[0] = a.x; Lq[1] = a.y; Lq[2] = a.z; Lq[3] = a.w;
            Lq[4] = b.x; Lq[5] = b.y; Lq[6] = b.z; Lq[7] = b.w;
            __syncthreads();
            const int f = t & 31, koct = t >> 5;
            const int nt = f >> 4;
            const int kg = d0 + koct * 8;
            const int kslice = kg >> 5;
            const int lane2 = (f & 15) | (((kg >> 3) & 3) << 4);
            uint4 o;
            o.x = pk2(Ltr[(koct * 8 + 0) * 33 + f], Ltr[(koct * 8 + 1) * 33 + f]);
            o.y = pk2(Ltr[(koct * 8 + 2) * 33 + f], Ltr[(koct * 8 + 3) * 33 + f]);
            o.z = pk2(Ltr[(koct * 8 + 4) * 33 + f], Ltr[(koct * 8 + 5) * 33 + f]);
            o.w = pk2(Ltr[(koct * 8 + 6) * 33 + f], Ltr[(koct * 8 + 7) * 33 + f]);
            *(uint4*)(f1F + ((((size_t)es * 2 + nt) * 32 + kslice) * 64 + lane2) * 8) = o;
        }
    } else {
        float* Ltr = smem;   // [64][33]
        const int i2 = blockIdx.x - 768;
        const int es = i2 >> 2;
        const int dq = i2 & 3;
        for (int d0 = dq * 256; d0 < dq * 256 + 256; d0 += 64) {
            const int f = t >> 3, ds = (t & 7) * 8;
            const float* src = f2 + (size_t)es * (FF * DM) + f * DM + d0 + ds;
            float4 a = *(const float4*)src;
            float4 b = *(const float4*)(src + 4);
            __syncthreads();
            Ltr[(ds + 0) * 33 + f] = a.x; Ltr[(ds + 1) * 33 + f] = a.y;
            Ltr[(ds + 2) * 33 + f] = a.z; Ltr[(ds + 3) * 33 + f] = a.w;
            Ltr[(ds + 4) * 33 + f] = b.x; Ltr[(ds + 5) * 33 + f] = b.y;
            Ltr[(ds + 6) * 33 + f] = b.z; Ltr[(ds + 7) * 33 + f] = b.w;
            __syncthreads();
            const int dd = t >> 2, f0 = (t & 3) * 8;
            uint4 o;
            o.x = pk2(Ltr[dd * 33 + f0 + 0], Ltr[dd * 33 + f0 + 1]);
            o.y = pk2(Ltr[dd * 33 + f0 + 2], Ltr[dd * 33 + f0 + 3]);
            o.z = pk2(Ltr[dd * 33 + f0 + 4], Ltr[dd * 33 + f0 + 5]);
            o.w = pk2(Ltr[dd * 33 + f0 + 6], Ltr[dd * 33 + f0 + 7]);
            *(uint4*)(f2T + (size_t)es * (FF * DM) + (d0 + dd) * FF + f0) = o;
        }
    }
}

// ---------------------------------------------------------------------------
// K2: H = relu(x_gathered @ f1 + bias) via MFMA. LDS-free. UNCHANGED (v18).
// ---------------------------------------------------------------------------
__global__ __launch_bounds__(256) void k_h_mfma(
    const ushort* __restrict__ xb, const ushort* __restrict__ f1F,
    const float* __restrict__ bias, const int* __restrict__ idx,
    ushort* __restrict__ Hb)
{
    const int es = blockIdx.x >> 2;
    const int gq = blockIdx.x & 3;
    const int w = threadIdx.x >> 6;
    const int lane = threadIdx.x & 63;
    const int lrow = lane & 15;
    const int lk8 = (lane >> 4) * 8;

    const int ga = gq * 64 + w * 16 + lrow;
    const int tok = idx[ga * NSLOT + es];
    const ushort* abase = xb + ((size_t)ga * TG + tok) * DM + lk8;
    const ushort* bbase = f1F + (size_t)es * 2 * 32 * 512 + (size_t)lane * 8;

    f32x4 acc[2] = {(f32x4){0.f, 0.f, 0.f, 0.f}, (f32x4){0.f, 0.f, 0.f, 0.f}};

#pragma unroll 4
    for (int kslice = 0; kslice < 32; ++kslice) {
        const bf16x8 A = *(const bf16x8*)(abase + kslice * 32);
#pragma unroll
        for (int nt = 0; nt < 2; ++nt) {
            const bf16x8 B = *(const bf16x8*)(bbase + ((size_t)nt * 32 + kslice) * 512);
            acc[nt] = __builtin_amdgcn_mfma_f32_16x16x32_bf16(A, B, acc[nt], 0, 0, 0);
        }
    }

#pragma unroll
    for (int nt = 0; nt < 2; ++nt) {
        const int f = nt * 16 + lrow;
        const float bv = bias[es * FF + f];
#pragma unroll
        for (int r = 0; r < 4; ++r) {
            const int g = gq * 64 + w * 16 + (lane >> 4) * 4 + r;
            const float hv = fmaxf(acc[nt][r] + bv, 0.0f);
            Hb[(size_t)g * (NSLOT * FF) + es * FF + f] = f2bf(hv);
        }
    }
}

// ---------------------------------------------------------------------------
// K3 (v20): v18 structure + ONE change: the OL read-modify-write is deferred
// by one es (software pipeline). At iter e the wave issues {fragA_e, fragB_e,
// OLread_{e-1}} together -> a single lgkmcnt stall covers all three, instead
// of two serial LDS-latency stalls per es. In-order lgkm completion keeps
// same-address RMWs ordered even when consecutive es hit the same token row;
// every add executes in the same order with the same operands -> output
// bit-identical. First iteration does a benign +0.0 RMW to the lane's own
// t=0 slot (x + 0.0f is exact); final RMW drains after the loop.
// ---------------------------------------------------------------------------
__global__ __launch_bounds__(256) void k_out_mfma(
    const ushort* __restrict__ Hb, const ushort* __restrict__ f2T,
    const uchar* __restrict__ idx8, float* __restrict__ out)
{
    extern __shared__ char smK3[];
    float* OL   = (float*)smK3;                // [32 t][256 16B-slots] = 128 KB
    char*  Ring = smK3 + 131072;               // [4 w][4 slots][2048 B] = 32 KB

    const int D0 = (blockIdx.x & 15) * 64;     // db-minor (proven order)
    const int G0 = (blockIdx.x >> 4) * 16;
    const int tid = threadIdx.x;
    const int w = tid >> 6;
    const int lane = tid & 63;
    const int gl = lane & 15;                  // group (B col) AND A d-row
    const int sq = lane >> 4;                  // k-slice 0..3
    const int dq = w * 4 + sq;                 // d-quad 0..15

    for (int i = tid * 4; i < 32768; i += 1024)
        *(f32x4*)&OL[i] = (f32x4){0.f, 0.f, 0.f, 0.f};
    uint ui[32];
    {
        const uint4* p = (const uint4*)(idx8 + (size_t)(G0 + gl) * NSLOT);
#pragma unroll
        for (int k = 0; k < 8; ++k) {
            const uint4 v = p[k];
            ui[k * 4 + 0] = v.x; ui[k * 4 + 1] = v.y;
            ui[k * 4 + 2] = v.z; ui[k * 4 + 3] = v.w;
        }
    }
    __syncthreads();

    const ushort* ap  = f2T + (size_t)(D0 + w * 16 + gl) * FF + sq * 8;
    const ushort* bps = Hb + (size_t)(G0 + gl) * (NSLOT * FF) + sq * 8;
    char* ring = Ring + w * 8192;

#pragma unroll
    for (int s = 0; s < 3; ++s) {
        gload_lds16(ap  + (size_t)s * (FF * DM), ring + s * 2048);
        gload_lds16(bps + (size_t)s * FF,        ring + s * 2048 + 1024);
    }

    const int sOL = (dq << 4) | (dq ^ gl);

    // deferred-RMW pipeline state (dummy first target: lane's own t=0 slot)
    f32x4 dprev = (f32x4){0.f, 0.f, 0.f, 0.f};
    float* olp_prev = &OL[sOL * 4];

#pragma unroll 4
    for (int e = 0; e < 128; ++e) {
        {
            const int en = (e + 3) & 127;
            char* slot = ring + ((e + 3) & 3) * 2048;
            gload_lds16(ap  + (size_t)en * (FF * DM), slot);
            gload_lds16(bps + (size_t)en * FF,        slot + 1024);
        }
        asm volatile("s_waitcnt vmcnt(6)" ::: "memory");

        const char* slot = ring + (e & 3) * 2048;
        const bf16x8 afr = *(const bf16x8*)(slot + lane * 16);
        const bf16x8 bfr = *(const bf16x8*)(slot + 1024 + lane * 16);
        // RMW of previous es: its OLread is issued alongside afr/bfr, so one
        // lgkm wait covers all three LDS reads.
        *(f32x4*)olp_prev = *(const f32x4*)olp_prev + dprev;
        const f32x4 d = __builtin_amdgcn_mfma_f32_16x16x32_bf16(
            afr, bfr, (f32x4){0.f, 0.f, 0.f, 0.f}, 0, 0, 0);
        const uint tv = (ui[e >> 2] >> ((e & 3) * 8)) & 0xFFu;
        olp_prev = &OL[tv * 1024 + sOL * 4];
        dprev = d;
    }
    // drain the last deferred RMW
    *(f32x4*)olp_prev = *(const f32x4*)olp_prev + dprev;
    asm volatile("s_waitcnt vmcnt(0)" ::: "memory");
    __syncthreads();

    {
        const int g = tid >> 4, dqe = tid & 15;
        const int se = (dqe << 4) | (dqe ^ g);
#pragma unroll 4
        for (int t = 0; t < TG; ++t) {
            const f32x4 v = *(const f32x4*)&OL[t * 1024 + se * 4];
            *(f32x4*)&out[((size_t)(G0 + g) * TG + t) * DM + D0 + dqe * 4] = v;
        }
    }
}

// ---------------------------------------------------------------------------
extern "C" void kernel_launch(void* const* d_in, const int* in_sizes, int n_in,
                              void* d_out, int out_size, void* d_ws, size_t ws_size,
                              hipStream_t stream) {
    (void)in_sizes; (void)n_in; (void)out_size; (void)ws_size;
    const float* x    = (const float*)d_in[0];
    const float* ctrl = (const float*)d_in[1];
    const float* f1   = (const float*)d_in[2];
    const float* bias = (const float*)d_in[3];
    const float* f2   = (const float*)d_in[4];
    float* out = (float*)d_out;

    char* ws = (char*)d_ws;
    int*    idx  = (int*)ws;                        // 128 KB
    ushort* Hb   = (ushort*)(ws + 131072);          // 2 MB
    ushort* f1F  = (ushort*)(ws + 2228224);         // 8 MB
    ushort* f2T  = (ushort*)(ws + 10616832);        // 8 MB
    ushort* xb   = (ushort*)(ws + 19005440);        // 16 MB
    uchar*  idx8 = (uchar*)(ws + 35782656);         // 32 KB (end ~34.2 MB)

    k_fused1<<<1280, 256, 0, stream>>>(x, ctrl, f1, f2, idx, idx8, xb, f1F, f2T);

    k_h_mfma<<<NSLOT * 4, 256, 0, stream>>>(xb, f1F, bias, idx, Hb);

    const size_t lds3 = 163840;                     // 160 KiB exactly
    hipFuncSetAttribute((const void*)k_out_mfma,
                        hipFuncAttributeMaxDynamicSharedMemorySize, (int)lds3);
    k_out_mfma<<<256, 256, lds3, stream>>>(Hb, f2T, idx8, out);
}

// Round 21
// 68.757 us; speedup vs baseline: 1.7492x; 1.0952x over previous
//
#include <hip/hip_runtime.h>
#include <hip/hip_bf16.h>

#define NGROUP 256   // B * (SEQ/TG)
#define NSLOT  128   // experts * sets
#define TG     32    // tokens per group
#define DM     1024  // model dim
#define FF     32    // expert size

#define LSCALE     4096.0f
#define INV_LSCALE (1.0f / 4096.0f)

typedef unsigned int  uint;
typedef unsigned short ushort;
typedef unsigned char uchar;
typedef __attribute__((ext_vector_type(4))) float f32x4;
typedef __attribute__((ext_vector_type(8))) short bf16x8;
typedef __attribute__((ext_vector_type(8))) _Float16 f16x8;

__device__ __forceinline__ ushort f2bf(float f) {
    uint u = __float_as_uint(f);
    u += 0x7FFFu + ((u >> 16) & 1u);   // RNE
    return (ushort)(u >> 16);
}
__device__ __forceinline__ uint pk2(float a, float b) {
    return (uint)f2bf(a) | ((uint)f2bf(b) << 16);
}

// async global->LDS, 16B per lane; dst wave-uniform base (+lane*16 implicit)
__device__ __forceinline__ void gload_lds16(const void* g, void* l) {
    __builtin_amdgcn_global_load_lds(
        (const __attribute__((address_space(1))) uint*)g,
        (__attribute__((address_space(3))) uint*)l, 16, 0, 0);
}

// ---------------------------------------------------------------------------
// K1 mega-kernel (v18-proven, UNCHANGED): one launch, three block families.
//  blocks 0..511    : logits + tie-broken argmax + fused x->bf16 cast (+idx8)
//  blocks 512..767  : f1 -> f1F bf16 (MFMA-B fragment order)
//  blocks 768..1279 : f2 -> f2T[es][d][f] bf16
// ---------------------------------------------------------------------------
__global__ __launch_bounds__(256) void k_fused1(
    const float* __restrict__ x, const float* __restrict__ ctrl,
    const float* __restrict__ f1, const float* __restrict__ f2,
    int* __restrict__ idx, uchar* __restrict__ idx8, ushort* __restrict__ xb,
    ushort* __restrict__ f1F, ushort* __restrict__ f2T)
{
    __shared__ float smem[4 * 32 * 64];   // 32 KB
    const int t = threadIdx.x;

    if (blockIdx.x < 512) {
        float* Lp = smem;
        const int g  = blockIdx.x >> 1;
        const int nh = blockIdx.x & 1;
        const int w = t >> 6;
        const int lane = t & 63;
        const int lrow = lane & 15;
        const int lk8 = (lane >> 4) * 8;

        const size_t xoff0 = ((size_t)g * TG + lrow) * DM + w * 256 + lk8;
        const float* xr0 = x + xoff0;
        const float* xr1 = xr0 + 16 * DM;

        f32x4 ahh[2][4], ax[2][4];
#pragma unroll
        for (int mt = 0; mt < 2; ++mt)
#pragma unroll
            for (int nt = 0; nt < 4; ++nt) {
                ahh[mt][nt] = (f32x4){0.f, 0.f, 0.f, 0.f};
                ax[mt][nt]  = (f32x4){0.f, 0.f, 0.f, 0.f};
            }

        for (int ks = 0; ks < 8; ++ks) {
            f16x8 Ah[2], Al[2];
#pragma unroll
            for (int mt = 0; mt < 2; ++mt) {
                const float* p = (mt ? xr1 : xr0) + ks * 32;
                float xe[8];
                *(float4*)&xe[0] = *(const float4*)p;
                *(float4*)&xe[4] = *(const float4*)(p + 4);
                union { f16x8 v; _Float16 e[8]; } H, L;
#pragma unroll
                for (int j = 0; j < 8; ++j) {
                    const _Float16 h = (_Float16)xe[j];
                    H.e[j] = h;
                    L.e[j] = (_Float16)((xe[j] - (float)h) * LSCALE);
                }
                Ah[mt] = H.v; Al[mt] = L.v;
                if (nh == 0) {
                    uint4 o;
                    o.x = pk2(xe[0], xe[1]); o.y = pk2(xe[2], xe[3]);
                    o.z = pk2(xe[4], xe[5]); o.w = pk2(xe[6], xe[7]);
                    *(uint4*)(xb + xoff0 + (size_t)mt * 16 * DM + ks * 32) = o;
                }
            }
            const int kslice = w * 8 + ks;
#pragma unroll
            for (int nt = 0; nt < 4; ++nt) {
                const float* cp = ctrl
                    + (size_t)(kslice * 32 + ((lane >> 4) << 3)) * NSLOT
                    + nh * 64 + nt * 16 + (lane & 15);
                union { f16x8 v; _Float16 e[8]; } BH, BL;
#pragma unroll
                for (int j = 0; j < 8; ++j) {
                    const float c = cp[(size_t)j * NSLOT];
                    const _Float16 h = (_Float16)c;
                    BH.e[j] = h;
                    BL.e[j] = (_Float16)((c - (float)h) * LSCALE);
                }
#pragma unroll
                for (int mt = 0; mt < 2; ++mt) {
                    ahh[mt][nt] = __builtin_amdgcn_mfma_f32_16x16x32_f16(Ah[mt], BH.v, ahh[mt][nt], 0, 0, 0);
                    ax[mt][nt]  = __builtin_amdgcn_mfma_f32_16x16x32_f16(Al[mt], BH.v, ax[mt][nt], 0, 0, 0);
                    ax[mt][nt]  = __builtin_amdgcn_mfma_f32_16x16x32_f16(Ah[mt], BL.v, ax[mt][nt], 0, 0, 0);
                }
            }
        }

#pragma unroll
        for (int mt = 0; mt < 2; ++mt)
#pragma unroll
            for (int nt = 0; nt < 4; ++nt)
#pragma unroll
                for (int r = 0; r < 4; ++r) {
                    const int trow = mt * 16 + (lane >> 4) * 4 + r;
                    const int nl = nt * 16 + lrow;
                    Lp[(w * TG + trow) * 64 + nl] =
                        ahh[mt][nt][r] + ax[mt][nt][r] * INV_LSCALE;
                }
        __syncthreads();

        for (int i = t * 4; i < TG * 64; i += 256 * 4) {
            f32x4 s0 = *(const f32x4*)&Lp[i];
            f32x4 s1 = *(const f32x4*)&Lp[2048 + i];
            f32x4 s2 = *(const f32x4*)&Lp[4096 + i];
            f32x4 s3 = *(const f32x4*)&Lp[6144 + i];
            *(f32x4*)&Lp[i] = (s0 + s1) + (s2 + s3);
        }
        __syncthreads();

        if (t < 64) {
            const int n = t;
            float best = -1e30f;
            int bi = 0;
#pragma unroll
            for (int tt = 0; tt < TG; ++tt) {
                const float v = Lp[tt * 64 + n] + (float)tt * (1e-6f / 31.0f);
                if (v >= best) { best = v; bi = tt; }   // later token wins ties
            }
            idx[g * NSLOT + nh * 64 + n] = bi;
            idx8[g * NSLOT + nh * 64 + n] = (uchar)bi;
        }
    } else if (blockIdx.x < 768) {
        float* Ltr = smem;   // [64][33]
        const int i1 = blockIdx.x - 512;
        const int es = i1 >> 1;
        const int dh = i1 & 1;
        for (int d0 = dh * 512; d0 < dh * 512 + 512; d0 += 64) {
            const int dd = t >> 2, f0 = (t & 3) * 8;
            const float* src = f1 + (size_t)(d0 + dd) * 4096 + es * FF + f0;
            float4 a = *(const float4*)src;
            float4 b = *(const float4*)(src + 4);
            __syncthreads();
            float* Lq = &Ltr[dd * 33 + f0];
            Lq[0] = a.x; Lq[1] = a.y; Lq[2] = a.z; Lq[3] = a.w;
            Lq[4] = b.x; Lq[5] = b.y; Lq[6] = b.z; Lq[7] = b.w;
            __syncthreads();
            const int f = t & 31, koct = t >> 5;
            const int nt = f >> 4;
            const int kg = d0 + koct * 8;
            const int kslice = kg >> 5;
            const int lane2 = (f & 15) | (((kg >> 3) & 3) << 4);
            uint4 o;
            o.x = pk2(Ltr[(koct * 8 + 0) * 33 + f], Ltr[(koct * 8 + 1) * 33 + f]);
            o.y = pk2(Ltr[(koct * 8 + 2) * 33 + f], Ltr[(koct * 8 + 3) * 33 + f]);
            o.z = pk2(Ltr[(koct * 8 + 4) * 33 + f], Ltr[(koct * 8 + 5) * 33 + f]);
            o.w = pk2(Ltr[(koct * 8 + 6) * 33 + f], Ltr[(koct * 8 + 7) * 33 + f]);
            *(uint4*)(f1F + ((((size_t)es * 2 + nt) * 32 + kslice) * 64 + lane2) * 8) = o;
        }
    } else {
        float* Ltr = smem;   // [64][33]
        const int i2 = blockIdx.x - 768;
        const int es = i2 >> 2;
        const int dq = i2 & 3;
        for (int d0 = dq * 256; d0 < dq * 256 + 256; d0 += 64) {
            const int f = t >> 3, ds = (t & 7) * 8;
            const float* src = f2 + (size_t)es * (FF * DM) + f * DM + d0 + ds;
            float4 a = *(const float4*)src;
            float4 b = *(const float4*)(src + 4);
            __syncthreads();
            Ltr[(ds + 0) * 33 + f] = a.x; Ltr[(ds + 1) * 33 + f] = a.y;
            Ltr[(ds + 2) * 33 + f] = a.z; Ltr[(ds + 3) * 33 + f] = a.w;
            Ltr[(ds + 4) * 33 + f] = b.x; Ltr[(ds + 5) * 33 + f] = b.y;
            Ltr[(ds + 6) * 33 + f] = b.z; Ltr[(ds + 7) * 33 + f] = b.w;
            __syncthreads();
            const int dd = t >> 2, f0 = (t & 3) * 8;
            uint4 o;
            o.x = pk2(Ltr[dd * 33 + f0 + 0], Ltr[dd * 33 + f0 + 1]);
            o.y = pk2(Ltr[dd * 33 + f0 + 2], Ltr[dd * 33 + f0 + 3]);
            o.z = pk2(Ltr[dd * 33 + f0 + 4], Ltr[dd * 33 + f0 + 5]);
            o.w = pk2(Ltr[dd * 33 + f0 + 6], Ltr[dd * 33 + f0 + 7]);
            *(uint4*)(f2T + (size_t)es * (FF * DM) + (d0 + dd) * FF + f0) = o;
        }
    }
}

// ---------------------------------------------------------------------------
// K2: H = relu(x_gathered @ f1 + bias) via MFMA. LDS-free. v21: output now
// written TRANSPOSED as HbT[es][g][f] (es-major) so k_out's per-es B-slice
// is one contiguous 1 KB block. Values identical; only the layout changes.
// ---------------------------------------------------------------------------
__global__ __launch_bounds__(256) void k_h_mfma(
    const ushort* __restrict__ xb, const ushort* __restrict__ f1F,
    const float* __restrict__ bias, const int* __restrict__ idx,
    ushort* __restrict__ HbT)
{
    const int es = blockIdx.x >> 2;
    const int gq = blockIdx.x & 3;
    const int w = threadIdx.x >> 6;
    const int lane = threadIdx.x & 63;
    const int lrow = lane & 15;
    const int lk8 = (lane >> 4) * 8;

    const int ga = gq * 64 + w * 16 + lrow;
    const int tok = idx[ga * NSLOT + es];
    const ushort* abase = xb + ((size_t)ga * TG + tok) * DM + lk8;
    const ushort* bbase = f1F + (size_t)es * 2 * 32 * 512 + (size_t)lane * 8;

    f32x4 acc[2] = {(f32x4){0.f, 0.f, 0.f, 0.f}, (f32x4){0.f, 0.f, 0.f, 0.f}};

#pragma unroll 4
    for (int kslice = 0; kslice < 32; ++kslice) {
        const bf16x8 A = *(const bf16x8*)(abase + kslice * 32);
#pragma unroll
        for (int nt = 0; nt < 2; ++nt) {
            const bf16x8 B = *(const bf16x8*)(bbase + ((size_t)nt * 32 + kslice) * 512);
            acc[nt] = __builtin_amdgcn_mfma_f32_16x16x32_bf16(A, B, acc[nt], 0, 0, 0);
        }
    }

#pragma unroll
    for (int nt = 0; nt < 2; ++nt) {
        const int f = nt * 16 + lrow;
        const float bv = bias[es * FF + f];
#pragma unroll
        for (int r = 0; r < 4; ++r) {
            const int g = gq * 64 + w * 16 + (lane >> 4) * 4 + r;
            const float hv = fmaxf(acc[nt][r] + bv, 0.0f);
            HbT[(size_t)es * (NGROUP * FF) + g * FF + f] = f2bf(hv);
        }
    }
}

// ---------------------------------------------------------------------------
// K3 (v21): v18 structure with ONE change: B is staged from es-major
// HbT[es][g][f], so each per-es B gload is a single contiguous 1 KB block
// per wave (v18's was 16 scattered 64-B segments across 128 KB -> 16
// transactions per load). Per-lane values identical -> output bit-identical.
// ---------------------------------------------------------------------------
__global__ __launch_bounds__(256) void k_out_mfma(
    const ushort* __restrict__ HbT, const ushort* __restrict__ f2T,
    const uchar* __restrict__ idx8, float* __restrict__ out)
{
    extern __shared__ char smK3[];
    float* OL   = (float*)smK3;                // [32 t][256 16B-slots] = 128 KB
    char*  Ring = smK3 + 131072;               // [4 w][4 slots][2048 B] = 32 KB

    const int D0 = (blockIdx.x & 15) * 64;     // db-minor (proven order)
    const int G0 = (blockIdx.x >> 4) * 16;
    const int tid = threadIdx.x;
    const int w = tid >> 6;
    const int lane = tid & 63;
    const int gl = lane & 15;                  // group (B col) AND A d-row
    const int sq = lane >> 4;                  // k-slice 0..3
    const int dq = w * 4 + sq;                 // d-quad 0..15

    for (int i = tid * 4; i < 32768; i += 1024)
        *(f32x4*)&OL[i] = (f32x4){0.f, 0.f, 0.f, 0.f};
    uint ui[32];
    {
        const uint4* p = (const uint4*)(idx8 + (size_t)(G0 + gl) * NSLOT);
#pragma unroll
        for (int k = 0; k < 8; ++k) {
            const uint4 v = p[k];
            ui[k * 4 + 0] = v.x; ui[k * 4 + 1] = v.y;
            ui[k * 4 + 2] = v.z; ui[k * 4 + 3] = v.w;
        }
    }
    __syncthreads();

    const ushort* ap  = f2T + (size_t)(D0 + w * 16 + gl) * FF + sq * 8;
    const ushort* bps = HbT + (size_t)(G0 + gl) * FF + sq * 8;   // + es*(NGROUP*FF)
    char* ring = Ring + w * 8192;

#pragma unroll
    for (int s = 0; s < 3; ++s) {
        gload_lds16(ap  + (size_t)s * (FF * DM),     ring + s * 2048);
        gload_lds16(bps + (size_t)s * (NGROUP * FF), ring + s * 2048 + 1024);
    }

    const int sOL = (dq << 4) | (dq ^ gl);

#pragma unroll 4
    for (int e = 0; e < 128; ++e) {
        {
            const int en = (e + 3) & 127;
            char* slot = ring + ((e + 3) & 3) * 2048;
            gload_lds16(ap  + (size_t)en * (FF * DM),     slot);
            gload_lds16(bps + (size_t)en * (NGROUP * FF), slot + 1024);
        }
        asm volatile("s_waitcnt vmcnt(6)" ::: "memory");

        const char* slot = ring + (e & 3) * 2048;
        const bf16x8 afr = *(const bf16x8*)(slot + lane * 16);
        const bf16x8 bfr = *(const bf16x8*)(slot + 1024 + lane * 16);
        const f32x4 d = __builtin_amdgcn_mfma_f32_16x16x32_bf16(
            afr, bfr, (f32x4){0.f, 0.f, 0.f, 0.f}, 0, 0, 0);
        const uint tv = (ui[e >> 2] >> ((e & 3) * 8)) & 0xFFu;
        float* olp = &OL[tv * 1024 + sOL * 4];
        *(f32x4*)olp = *(const f32x4*)olp + d;
    }
    asm volatile("s_waitcnt vmcnt(0)" ::: "memory");
    __syncthreads();

    {
        const int g = tid >> 4, dqe = tid & 15;
        const int se = (dqe << 4) | (dqe ^ g);
#pragma unroll 4
        for (int t = 0; t < TG; ++t) {
            const f32x4 v = *(const f32x4*)&OL[t * 1024 + se * 4];
            *(f32x4*)&out[((size_t)(G0 + g) * TG + t) * DM + D0 + dqe * 4] = v;
        }
    }
}

// ---------------------------------------------------------------------------
extern "C" void kernel_launch(void* const* d_in, const int* in_sizes, int n_in,
                              void* d_out, int out_size, void* d_ws, size_t ws_size,
                              hipStream_t stream) {
    (void)in_sizes; (void)n_in; (void)out_size; (void)ws_size;
    const float* x    = (const float*)d_in[0];
    const float* ctrl = (const float*)d_in[1];
    const float* f1   = (const float*)d_in[2];
    const float* bias = (const float*)d_in[3];
    const float* f2   = (const float*)d_in[4];
    float* out = (float*)d_out;

    char* ws = (char*)d_ws;
    int*    idx  = (int*)ws;                        // 128 KB
    ushort* HbT  = (ushort*)(ws + 131072);          // 2 MB  ([es][g][f])
    ushort* f1F  = (ushort*)(ws + 2228224);         // 8 MB
    ushort* f2T  = (ushort*)(ws + 10616832);        // 8 MB
    ushort* xb   = (ushort*)(ws + 19005440);        // 16 MB
    uchar*  idx8 = (uchar*)(ws + 35782656);         // 32 KB (end ~34.2 MB)

    k_fused1<<<1280, 256, 0, stream>>>(x, ctrl, f1, f2, idx, idx8, xb, f1F, f2T);

    k_h_mfma<<<NSLOT * 4, 256, 0, stream>>>(xb, f1F, bias, idx, HbT);

    const size_t lds3 = 163840;                     // 160 KiB exactly
    hipFuncSetAttribute((const void*)k_out_mfma,
                        hipFuncAttributeMaxDynamicSharedMemorySize, (int)lds3);
    k_out_mfma<<<256, 256, lds3, stream>>>(HbT, f2T, idx8, out);
}

// Round 22
// 68.372 us; speedup vs baseline: 1.7591x; 1.0056x over previous
//
#include <hip/hip_runtime.h>
#include <hip/hip_bf16.h>

#define NGROUP 256   // B * (SEQ/TG)
#define NSLOT  128   // experts * sets
#define TG     32    // tokens per group
#define DM     1024  // model dim
#define FF     32    // expert size

#define LSCALE     4096.0f
#define INV_LSCALE (1.0f / 4096.0f)

typedef unsigned int  uint;
typedef unsigned short ushort;
typedef unsigned char uchar;
typedef __attribute__((ext_vector_type(4))) float f32x4;
typedef __attribute__((ext_vector_type(8))) short bf16x8;
typedef __attribute__((ext_vector_type(8))) _Float16 f16x8;

__device__ __forceinline__ ushort f2bf(float f) {
    uint u = __float_as_uint(f);
    u += 0x7FFFu + ((u >> 16) & 1u);   // RNE
    return (ushort)(u >> 16);
}
__device__ __forceinline__ uint pk2(float a, float b) {
    return (uint)f2bf(a) | ((uint)f2bf(b) << 16);
}

// async global->LDS, 16B per lane; dst wave-uniform base (+lane*16 implicit)
__device__ __forceinline__ void gload_lds16(const void* g, void* l) {
    __builtin_amdgcn_global_load_lds(
        (const __attribute__((address_space(1))) uint*)g,
        (__attribute__((address_space(3))) uint*)l, 16, 0, 0);
}

// ---------------------------------------------------------------------------
// Launch 1: logits + argmax + x->bf16 (blocks 0..511)  ||  f1->f1F (512..767)
// v22: ctrl raw loads for a k-slice are hoisted into registers BEFORE the
// split/MFMA cluster (32-deep MLP instead of 8). Same values, same FMA
// order -> idx/xb bit-identical to v21.
// ---------------------------------------------------------------------------
__global__ __launch_bounds__(256) void k_fused1(
    const float* __restrict__ x, const float* __restrict__ ctrl,
    const float* __restrict__ f1,
    int* __restrict__ idx, uchar* __restrict__ idx8, ushort* __restrict__ xb,
    ushort* __restrict__ f1F)
{
    __shared__ float smem[4 * 32 * 64];   // 32 KB
    const int t = threadIdx.x;

    if (blockIdx.x < 512) {
        float* Lp = smem;
        const int g  = blockIdx.x >> 1;
        const int nh = blockIdx.x & 1;
        const int w = t >> 6;
        const int lane = t & 63;
        const int lrow = lane & 15;
        const int lk8 = (lane >> 4) * 8;

        const size_t xoff0 = ((size_t)g * TG + lrow) * DM + w * 256 + lk8;
        const float* xr0 = x + xoff0;
        const float* xr1 = xr0 + 16 * DM;

        f32x4 ahh[2][4], ax[2][4];
#pragma unroll
        for (int mt = 0; mt < 2; ++mt)
#pragma unroll
            for (int nt = 0; nt < 4; ++nt) {
                ahh[mt][nt] = (f32x4){0.f, 0.f, 0.f, 0.f};
                ax[mt][nt]  = (f32x4){0.f, 0.f, 0.f, 0.f};
            }

        for (int ks = 0; ks < 8; ++ks) {
            f16x8 Ah[2], Al[2];
#pragma unroll
            for (int mt = 0; mt < 2; ++mt) {
                const float* p = (mt ? xr1 : xr0) + ks * 32;
                float xe[8];
                *(float4*)&xe[0] = *(const float4*)p;
                *(float4*)&xe[4] = *(const float4*)(p + 4);
                union { f16x8 v; _Float16 e[8]; } H, L;
#pragma unroll
                for (int j = 0; j < 8; ++j) {
                    const _Float16 h = (_Float16)xe[j];
                    H.e[j] = h;
                    L.e[j] = (_Float16)((xe[j] - (float)h) * LSCALE);
                }
                Ah[mt] = H.v; Al[mt] = L.v;
                if (nh == 0) {
                    uint4 o;
                    o.x = pk2(xe[0], xe[1]); o.y = pk2(xe[2], xe[3]);
                    o.z = pk2(xe[4], xe[5]); o.w = pk2(xe[6], xe[7]);
                    *(uint4*)(xb + xoff0 + (size_t)mt * 16 * DM + ks * 32) = o;
                }
            }
            const int kslice = w * 8 + ks;
            // hoist ALL ctrl raw loads for this k-slice (4 nt x 8 j = 32-deep)
            float craw[4][8];
#pragma unroll
            for (int nt = 0; nt < 4; ++nt) {
                const float* cp = ctrl
                    + (size_t)(kslice * 32 + ((lane >> 4) << 3)) * NSLOT
                    + nh * 64 + nt * 16 + (lane & 15);
#pragma unroll
                for (int j = 0; j < 8; ++j)
                    craw[nt][j] = cp[(size_t)j * NSLOT];
            }
#pragma unroll
            for (int nt = 0; nt < 4; ++nt) {
                union { f16x8 v; _Float16 e[8]; } BH, BL;
#pragma unroll
                for (int j = 0; j < 8; ++j) {
                    const float c = craw[nt][j];
                    const _Float16 h = (_Float16)c;
                    BH.e[j] = h;
                    BL.e[j] = (_Float16)((c - (float)h) * LSCALE);
                }
#pragma unroll
                for (int mt = 0; mt < 2; ++mt) {
                    ahh[mt][nt] = __builtin_amdgcn_mfma_f32_16x16x32_f16(Ah[mt], BH.v, ahh[mt][nt], 0, 0, 0);
                    ax[mt][nt]  = __builtin_amdgcn_mfma_f32_16x16x32_f16(Al[mt], BH.v, ax[mt][nt], 0, 0, 0);
                    ax[mt][nt]  = __builtin_amdgcn_mfma_f32_16x16x32_f16(Ah[mt], BL.v, ax[mt][nt], 0, 0, 0);
                }
            }
        }

#pragma unroll
        for (int mt = 0; mt < 2; ++mt)
#pragma unroll
            for (int nt = 0; nt < 4; ++nt)
#pragma unroll
                for (int r = 0; r < 4; ++r) {
                    const int trow = mt * 16 + (lane >> 4) * 4 + r;
                    const int nl = nt * 16 + lrow;
                    Lp[(w * TG + trow) * 64 + nl] =
                        ahh[mt][nt][r] + ax[mt][nt][r] * INV_LSCALE;
                }
        __syncthreads();

        for (int i = t * 4; i < TG * 64; i += 256 * 4) {
            f32x4 s0 = *(const f32x4*)&Lp[i];
            f32x4 s1 = *(const f32x4*)&Lp[2048 + i];
            f32x4 s2 = *(const f32x4*)&Lp[4096 + i];
            f32x4 s3 = *(const f32x4*)&Lp[6144 + i];
            *(f32x4*)&Lp[i] = (s0 + s1) + (s2 + s3);
        }
        __syncthreads();

        if (t < 64) {
            const int n = t;
            float best = -1e30f;
            int bi = 0;
#pragma unroll
            for (int tt = 0; tt < TG; ++tt) {
                const float v = Lp[tt * 64 + n] + (float)tt * (1e-6f / 31.0f);
                if (v >= best) { best = v; bi = tt; }   // later token wins ties
            }
            idx[g * NSLOT + nh * 64 + n] = bi;
            idx8[g * NSLOT + nh * 64 + n] = (uchar)bi;
        }
    } else {
        float* Ltr = smem;   // [64][33]
        const int i1 = blockIdx.x - 512;
        const int es = i1 >> 1;
        const int dh = i1 & 1;
        for (int d0 = dh * 512; d0 < dh * 512 + 512; d0 += 64) {
            const int dd = t >> 2, f0 = (t & 3) * 8;
            const float* src = f1 + (size_t)(d0 + dd) * 4096 + es * FF + f0;
            float4 a = *(const float4*)src;
            float4 b = *(const float4*)(src + 4);
            __syncthreads();
            float* Lq = &Ltr[dd * 33 + f0];
            Lq[0] = a.x; Lq[1] = a.y; Lq[2] = a.z; Lq[3] = a.w;
            Lq[4] = b.x; Lq[5] = b.y; Lq[6] = b.z; Lq[7] = b.w;
            __syncthreads();
            const int f = t & 31, koct = t >> 5;
            const int nt = f >> 4;
            const int kg = d0 + koct * 8;
            const int kslice = kg >> 5;
            const int lane2 = (f & 15) | (((kg >> 3) & 3) << 4);
            uint4 o;
            o.x = pk2(Ltr[(koct * 8 + 0) * 33 + f], Ltr[(koct * 8 + 1) * 33 + f]);
            o.y = pk2(Ltr[(koct * 8 + 2) * 33 + f], Ltr[(koct * 8 + 3) * 33 + f]);
            o.z = pk2(Ltr[(koct * 8 + 4) * 33 + f], Ltr[(koct * 8 + 5) * 33 + f]);
            o.w = pk2(Ltr[(koct * 8 + 6) * 33 + f], Ltr[(koct * 8 + 7) * 33 + f]);
            *(uint4*)(f1F + ((((size_t)es * 2 + nt) * 32 + kslice) * 64 + lane2) * 8) = o;
        }
    }
}

// ---------------------------------------------------------------------------
// Launch 2: k_h (blocks 0..511) || f2 -> f2T transpose (blocks 512..1023).
// f2T is consumed only by launch 3, so its HBM streaming overlaps k_h here.
// k_h identical to v21 (HbT es-major output).
// ---------------------------------------------------------------------------
__global__ __launch_bounds__(256) void k_h_mfma(
    const ushort* __restrict__ xb, const ushort* __restrict__ f1F,
    const float* __restrict__ bias, const int* __restrict__ idx,
    const float* __restrict__ f2,
    ushort* __restrict__ HbT, ushort* __restrict__ f2T)
{
    __shared__ float Ltr[64 * 33];
    const int t = threadIdx.x;

    if (blockIdx.x < 512) {
        const int es = blockIdx.x >> 2;
        const int gq = blockIdx.x & 3;
        const int w = t >> 6;
        const int lane = t & 63;
        const int lrow = lane & 15;
        const int lk8 = (lane >> 4) * 8;

        const int ga = gq * 64 + w * 16 + lrow;
        const int tok = idx[ga * NSLOT + es];
        const ushort* abase = xb + ((size_t)ga * TG + tok) * DM + lk8;
        const ushort* bbase = f1F + (size_t)es * 2 * 32 * 512 + (size_t)lane * 8;

        f32x4 acc[2] = {(f32x4){0.f, 0.f, 0.f, 0.f}, (f32x4){0.f, 0.f, 0.f, 0.f}};

#pragma unroll 4
        for (int kslice = 0; kslice < 32; ++kslice) {
            const bf16x8 A = *(const bf16x8*)(abase + kslice * 32);
#pragma unroll
            for (int nt = 0; nt < 2; ++nt) {
                const bf16x8 B = *(const bf16x8*)(bbase + ((size_t)nt * 32 + kslice) * 512);
                acc[nt] = __builtin_amdgcn_mfma_f32_16x16x32_bf16(A, B, acc[nt], 0, 0, 0);
            }
        }

#pragma unroll
        for (int nt = 0; nt < 2; ++nt) {
            const int f = nt * 16 + lrow;
            const float bv = bias[es * FF + f];
#pragma unroll
            for (int r = 0; r < 4; ++r) {
                const int g = gq * 64 + w * 16 + (lane >> 4) * 4 + r;
                const float hv = fmaxf(acc[nt][r] + bv, 0.0f);
                HbT[(size_t)es * (NGROUP * FF) + g * FF + f] = f2bf(hv);
            }
        }
    } else {
        const int i2 = blockIdx.x - 512;
        const int es = i2 >> 2;
        const int dq = i2 & 3;
        for (int d0 = dq * 256; d0 < dq * 256 + 256; d0 += 64) {
            const int f = t >> 3, ds = (t & 7) * 8;
            const float* src = f2 + (size_t)es * (FF * DM) + f * DM + d0 + ds;
            float4 a = *(const float4*)src;
            float4 b = *(const float4*)(src + 4);
            __syncthreads();
            Ltr[(ds + 0) * 33 + f] = a.x; Ltr[(ds + 1) * 33 + f] = a.y;
            Ltr[(ds + 2) * 33 + f] = a.z; Ltr[(ds + 3) * 33 + f] = a.w;
            Ltr[(ds + 4) * 33 + f] = b.x; Ltr[(ds + 5) * 33 + f] = b.y;
            Ltr[(ds + 6) * 33 + f] = b.z; Ltr[(ds + 7) * 33 + f] = b.w;
            __syncthreads();
            const int dd = t >> 2, f0 = (t & 3) * 8;
            uint4 o;
            o.x = pk2(Ltr[dd * 33 + f0 + 0], Ltr[dd * 33 + f0 + 1]);
            o.y = pk2(Ltr[dd * 33 + f0 + 2], Ltr[dd * 33 + f0 + 3]);
            o.z = pk2(Ltr[dd * 33 + f0 + 4], Ltr[dd * 33 + f0 + 5]);
            o.w = pk2(Ltr[dd * 33 + f0 + 6], Ltr[dd * 33 + f0 + 7]);
            *(uint4*)(f2T + (size_t)es * (FF * DM) + (d0 + dd) * FF + f0) = o;
        }
    }
}

// ---------------------------------------------------------------------------
// K3 (v21-proven, UNCHANGED): 16 distinct groups x 64 d, grid 256, A+B ring
// (both contiguous 1 KB/wave), OL swizzled, idx8 in registers.
// ---------------------------------------------------------------------------
__global__ __launch_bounds__(256) void k_out_mfma(
    const ushort* __restrict__ HbT, const ushort* __restrict__ f2T,
    const uchar* __restrict__ idx8, float* __restrict__ out)
{
    extern __shared__ char smK3[];
    float* OL   = (float*)smK3;                // [32 t][256 16B-slots] = 128 KB
    char*  Ring = smK3 + 131072;               // [4 w][4 slots][2048 B] = 32 KB

    const int D0 = (blockIdx.x & 15) * 64;     // db-minor (proven order)
    const int G0 = (blockIdx.x >> 4) * 16;
    const int tid = threadIdx.x;
    const int w = tid >> 6;
    const int lane = tid & 63;
    const int gl = lane & 15;                  // group (B col) AND A d-row
    const int sq = lane >> 4;                  // k-slice 0..3
    const int dq = w * 4 + sq;                 // d-quad 0..15

    for (int i = tid * 4; i < 32768; i += 1024)
        *(f32x4*)&OL[i] = (f32x4){0.f, 0.f, 0.f, 0.f};
    uint ui[32];
    {
        const uint4* p = (const uint4*)(idx8 + (size_t)(G0 + gl) * NSLOT);
#pragma unroll
        for (int k = 0; k < 8; ++k) {
            const uint4 v = p[k];
            ui[k * 4 + 0] = v.x; ui[k * 4 + 1] = v.y;
            ui[k * 4 + 2] = v.z; ui[k * 4 + 3] = v.w;
        }
    }
    __syncthreads();

    const ushort* ap  = f2T + (size_t)(D0 + w * 16 + gl) * FF + sq * 8;
    const ushort* bps = HbT + (size_t)(G0 + gl) * FF + sq * 8;   // + es*(NGROUP*FF)
    char* ring = Ring + w * 8192;

#pragma unroll
    for (int s = 0; s < 3; ++s) {
        gload_lds16(ap  + (size_t)s * (FF * DM),     ring + s * 2048);
        gload_lds16(bps + (size_t)s * (NGROUP * FF), ring + s * 2048 + 1024);
    }

    const int sOL = (dq << 4) | (dq ^ gl);

#pragma unroll 4
    for (int e = 0; e < 128; ++e) {
        {
            const int en = (e + 3) & 127;
            char* slot = ring + ((e + 3) & 3) * 2048;
            gload_lds16(ap  + (size_t)en * (FF * DM),     slot);
            gload_lds16(bps + (size_t)en * (NGROUP * FF), slot + 1024);
        }
        asm volatile("s_waitcnt vmcnt(6)" ::: "memory");

        const char* slot = ring + (e & 3) * 2048;
        const bf16x8 afr = *(const bf16x8*)(slot + lane * 16);
        const bf16x8 bfr = *(const bf16x8*)(slot + 1024 + lane * 16);
        const f32x4 d = __builtin_amdgcn_mfma_f32_16x16x32_bf16(
            afr, bfr, (f32x4){0.f, 0.f, 0.f, 0.f}, 0, 0, 0);
        const uint tv = (ui[e >> 2] >> ((e & 3) * 8)) & 0xFFu;
        float* olp = &OL[tv * 1024 + sOL * 4];
        *(f32x4*)olp = *(const f32x4*)olp + d;
    }
    asm volatile("s_waitcnt vmcnt(0)" ::: "memory");
    __syncthreads();

    {
        const int g = tid >> 4, dqe = tid & 15;
        const int se = (dqe << 4) | (dqe ^ g);
#pragma unroll 4
        for (int t = 0; t < TG; ++t) {
            const f32x4 v = *(const f32x4*)&OL[t * 1024 + se * 4];
            *(f32x4*)&out[((size_t)(G0 + g) * TG + t) * DM + D0 + dqe * 4] = v;
        }
    }
}

// ---------------------------------------------------------------------------
extern "C" void kernel_launch(void* const* d_in, const int* in_sizes, int n_in,
                              void* d_out, int out_size, void* d_ws, size_t ws_size,
                              hipStream_t stream) {
    (void)in_sizes; (void)n_in; (void)out_size; (void)ws_size;
    const float* x    = (const float*)d_in[0];
    const float* ctrl = (const float*)d_in[1];
    const float* f1   = (const float*)d_in[2];
    const float* bias = (const float*)d_in[3];
    const float* f2   = (const float*)d_in[4];
    float* out = (float*)d_out;

    char* ws = (char*)d_ws;
    int*    idx  = (int*)ws;                        // 128 KB
    ushort* HbT  = (ushort*)(ws + 131072);          // 2 MB  ([es][g][f])
    ushort* f1F  = (ushort*)(ws + 2228224);         // 8 MB
    ushort* f2T  = (ushort*)(ws + 10616832);        // 8 MB
    ushort* xb   = (ushort*)(ws + 19005440);        // 16 MB
    uchar*  idx8 = (uchar*)(ws + 35782656);         // 32 KB (end ~34.2 MB)

    k_fused1<<<768, 256, 0, stream>>>(x, ctrl, f1, idx, idx8, xb, f1F);

    k_h_mfma<<<1024, 256, 0, stream>>>(xb, f1F, bias, idx, f2, HbT, f2T);

    const size_t lds3 = 163840;                     // 160 KiB exactly
    hipFuncSetAttribute((const void*)k_out_mfma,
                        hipFuncAttributeMaxDynamicSharedMemorySize, (int)lds3);
    k_out_mfma<<<256, 256, lds3, stream>>>(HbT, f2T, idx8, out);
}